// Round 11
// baseline (100.888 us; speedup 1.0000x reference)
//
#include <hip/hip_runtime.h>

// ---------------------------------------------------------------------------
// CrossGraphNodeAttention: out = softmax(mask(Q K^T / 16)) V per batch
//   Q = A@Wq^T+bq, K = B@Wk^T+bk, V = B@Wv^T+bv;  B=8, N=2048, H=256
// Round 11: 4-waves/SIMD attn. r9/r10 diagnosis: MfmaUtil+VALUBusy ~= 46%
// == 2 waves/SIMD x ~23% duty each (serial chain per iter). Fix chain COUNT:
// QBLK=64 (4 warps x 16q, u=1 -> ~100 VGPR), KVBLK=32, single-buffered K/V
// (39KB LDS) -> 4 independent blocks/CU = 4 waves/SIMD. S=4, grid 1024.
// wprep/proj/combine unchanged from r10.
// ---------------------------------------------------------------------------

typedef __attribute__((ext_vector_type(8))) __bf16 bf16x8;
typedef __attribute__((ext_vector_type(4))) __bf16 bf16x4;
typedef __attribute__((ext_vector_type(4))) float f32x4;

#if __has_builtin(__builtin_amdgcn_exp2f)
#define EXP2(x) __builtin_amdgcn_exp2f(x)
#else
#define EXP2(x) exp2f(x)
#endif

#define MFMA16(a, b, c) __builtin_amdgcn_mfma_f32_16x16x32_bf16((a), (b), (c), 0, 0, 0)

typedef const __attribute__((address_space(1))) char gas_char;
typedef __attribute__((address_space(3))) char las_char;

// global -> LDS direct copy: 16B/lane, LDS dest = uniform base (+lane*16 HW).
static __device__ __forceinline__ void gload16(const void* g, void* l) {
  __builtin_amdgcn_global_load_lds((gas_char*)g, (las_char*)l, 16, 0, 0);
}

static __device__ __forceinline__ bf16x8 pack8(f32x4 a, f32x4 b) {
  bf16x8 r;
  r[0] = (__bf16)a[0]; r[1] = (__bf16)a[1]; r[2] = (__bf16)a[2]; r[3] = (__bf16)a[3];
  r[4] = (__bf16)b[0]; r[5] = (__bf16)b[1]; r[6] = (__bf16)b[2]; r[7] = (__bf16)b[3];
  return r;
}

// ---------------------------------------------------------------------------
// wprep: blocks 0..95 convert W (f32 -> bf16, pre-swizzled quarter layout,
// Wq scaled by log2e/16); blocks 96..159 build the mask bias.
// ---------------------------------------------------------------------------
__global__ __launch_bounds__(256) void wprep_kernel(
    const float* __restrict__ Wq, const float* __restrict__ Wk,
    const float* __restrict__ Wv, const int* __restrict__ mask,
    __bf16* __restrict__ Wb, float* __restrict__ mb) {
  const int bid = blockIdx.x;
  if (bid < 96) {
    int c = bid * 256 + threadIdx.x;  // chunk id, 8192 chunks per W
    int w_id = c >> 13;
    int j = c & 8191;
    const float* __restrict__ W = (w_id == 0) ? Wq : (w_id == 1 ? Wk : Wv);
    int n = j >> 5;
    int c5 = j & 31;
    int qtr = c5 >> 3;
    int k8 = (c5 & 7) << 3;
    const float* wp = &W[n * 256 + qtr * 64 + k8];
    f32x4 w0 = *(const f32x4*)wp;
    f32x4 w1 = *(const f32x4*)(wp + 4);
    if (w_id == 0) {
      const float cs = 0.090168440f;  // log2(e)/16
      w0[0] *= cs; w0[1] *= cs; w0[2] *= cs; w0[3] *= cs;
      w1[0] *= cs; w1[1] *= cs; w1[2] *= cs; w1[3] *= cs;
    }
    int kx = k8 ^ ((n & 7) << 3);
    *(bf16x8*)&Wb[(size_t)w_id * 65536 + qtr * 16384 + n * 64 + kx] =
        pack8(w0, w1);
  } else {
    int i = (bid - 96) * 256 + threadIdx.x;
    if (i < 8 * 2048) mb[i] = (mask[i] != 0) ? 0.0f : -1.0e30f;
  }
}

// ---------------------------------------------------------------------------
// Projection v2 (unchanged from r10): 768 blocks; X in registers; W quarters
// gload16-staged, double-buffered (2x32KB), 1 barrier/quarter.
// ---------------------------------------------------------------------------
__global__ __launch_bounds__(256, 2) void proj_kernel(
    const float* __restrict__ A, const float* __restrict__ Bm,
    const __bf16* __restrict__ Wb,
    const float* __restrict__ bq, const float* __restrict__ bk,
    const float* __restrict__ bv,
    __bf16* __restrict__ QF, __bf16* __restrict__ KF, __bf16* __restrict__ VF) {
  extern __shared__ char smem[];  // 2 x 32KB W quarter buffers
  const int pid = blockIdx.x;
  const int proj = pid >> 8;        // 0:Q 1:K 2:V
  const int rb = (pid & 255) << 6;  // row base in flattened [16384]
  const float* __restrict__ X = (proj == 0) ? A : Bm;
  const char* __restrict__ Wbp = (const char*)(Wb + (size_t)proj * 65536);
  const float* __restrict__ bias = (proj == 0) ? bq : (proj == 1 ? bk : bv);
  const int tid = threadIdx.x;
  const int w = tid >> 6, l = tid & 63, lo = l & 15, g = l >> 4;
  const int r0 = rb + w * 16;

  bf16x8 xf[8];
#pragma unroll
  for (int q8 = 0; q8 < 8; ++q8) {
    const float* xp = &X[(r0 + lo) * 256 + q8 * 32 + g * 8];
    xf[q8] = pack8(*(const f32x4*)xp, *(const f32x4*)(xp + 4));
  }

  f32x4 acc[16];
#pragma unroll
  for (int j = 0; j < 16; ++j) acc[j] = (f32x4){0.f, 0.f, 0.f, 0.f};

  #define STAGEW(qtr, buf)                                                    \
    {                                                                         \
      const char* gw = Wbp + (qtr)*32768 + w * 1024 + l * 16;                 \
      char* lw = smem + (buf)*32768 + w * 1024;                               \
      gload16(gw, lw);                                                        \
      gload16(gw + 4096, lw + 4096);                                          \
      gload16(gw + 8192, lw + 8192);                                          \
      gload16(gw + 12288, lw + 12288);                                        \
      gload16(gw + 16384, lw + 16384);                                        \
      gload16(gw + 20480, lw + 20480);                                        \
      gload16(gw + 24576, lw + 24576);                                        \
      gload16(gw + 28672, lw + 28672);                                        \
    }

  STAGEW(0, 0);
  __syncthreads();

  for (int qtr = 0; qtr < 4; ++qtr) {
    const int cur = qtr & 1;
    if (qtr < 3) STAGEW(qtr + 1, cur ^ 1);
    const __bf16* Wl = (const __bf16*)(smem + cur * 32768);
#pragma unroll
    for (int ks2 = 0; ks2 < 2; ++ks2) {
      bf16x8 xcur = xf[qtr * 2 + ks2];
#pragma unroll
      for (int nt = 0; nt < 16; ++nt) {
        int n = nt * 16 + lo;
        int kchunk = (ks2 * 4 + g) ^ (n & 7);
        bf16x8 wf = *(const bf16x8*)&Wl[n * 64 + kchunk * 8];
        if (proj == 2) {
          acc[nt] = MFMA16(wf, xcur, acc[nt]);
        } else {
          acc[nt] = MFMA16(xcur, wf, acc[nt]);
        }
      }
    }
    __syncthreads();
  }

  if (proj != 2) {
    const float cs = (proj == 0) ? 0.090168440f : 1.0f;  // bias scale
    __bf16* __restrict__ O = (proj == 0) ? QF : KF;
    const size_t rgbase = (size_t)(r0 >> 4) << 12;
#pragma unroll
    for (int nt = 0; nt < 16; ++nt) {
      int h = nt * 16 + lo;
      float bb = bias[h] * cs;
      size_t hpart = (size_t)((h >> 5) << 9) + (((h >> 3) & 3) << 7) + (h & 7);
#pragma unroll
      for (int r = 0; r < 4; ++r) {
        int R = r0 + g * 4 + r;
        O[rgbase + hpart + ((R & 15) << 3)] = (__bf16)(acc[nt][r] + bb);
      }
    }
  } else {
    const int bidx = r0 >> 11;
    const int nb = r0 & 2047;
    __bf16* __restrict__ Vo = VF + (size_t)bidx * 524288;
#pragma unroll
    for (int ht = 0; ht < 16; ++ht)
#pragma unroll
      for (int r = 0; r < 4; ++r) {
        int h = ht * 16 + g * 4 + r;
        int n = nb + lo;
        Vo[((size_t)(n >> 6) << 14) + ((h >> 4) << 10) + (((n >> 3) & 7) << 7) +
           ((h & 15) << 3) + (n & 7)] = (__bf16)(acc[ht][r] + bias[h]);
      }
  }
}

// ---------------------------------------------------------------------------
// Attention: grid = 8 b x 32 qt x S; 4 warps x 16 q-rows (QBLK=64).
// KVBLK=32 single-buffered: K 16KB + V 16KB + P 5KB + mbl 2KB = 39KB LDS
// -> 4 independent blocks/CU (16 waves/CU = 4/SIMD). Two barriers/iter;
// stage latency hidden by cross-block TLP.
// ---------------------------------------------------------------------------
__global__ __launch_bounds__(256, 4) void attn_kernel(
    const __bf16* __restrict__ QF, const __bf16* __restrict__ KF,
    const __bf16* __restrict__ VF, const float* __restrict__ mb,
    __bf16* __restrict__ Opart, float* __restrict__ mpart,
    float* __restrict__ lpart, float* __restrict__ out,
    int chunk, int direct) {
  extern __shared__ char smem[];  // [K 16K][V 16K][P 4x1280][mbl 2K]
  const int bid = blockIdx.x;
  const int b = bid & 7;            // batch -> XCD pinning
  const int rest = bid >> 3;
  const int qt = rest & 31;
  const int s = rest >> 5;
  const int tid = threadIdx.x;
  const int w = tid >> 6, l = tid & 63, lo = l & 15, g = l >> 4;
  const int q0 = qt * 64 + w * 16;
  const __bf16* __restrict__ Qb = QF + ((size_t)b * 2048 + q0) * 256;
  const __bf16* __restrict__ Kb = KF + (size_t)b * 2048 * 256;
  const __bf16* __restrict__ Vb = VF + (size_t)b * 524288;
  const float* __restrict__ mbb = mb + b * 2048;
  __bf16* Pw = (__bf16*)(smem + 32768) + w * 640;  // 16 rows, stride 40
  float* mbl = (float*)(smem + 37888);             // chunk<=512 floats

  bf16x8 qf[8];  // 16 q-rows, x32 B-operand frags
#pragma unroll
  for (int hs = 0; hs < 8; ++hs)
    qf[hs] = *(const bf16x8*)&Qb[hs * 512 + l * 8];

  f32x4 oacc[16];
#pragma unroll
  for (int i = 0; i < 16; ++i) oacc[i] = (f32x4){0.f, 0.f, 0.f, 0.f};
  float m = -3.0e28f, lsum = 0.f;

  const int kv0 = s * chunk;
  const int niter = chunk >> 5;

  // stage kv-32 tile (single buffer): warp w does 4 K + 4 V gload16.
  #define STAGE(kvb)                                                          \
    {                                                                         \
      const char* gk = (const char*)(Kb + (size_t)(kvb) * 256) + w * 4096 +   \
                       l * 16;                                                \
      char* lk = smem + w * 4096;                                             \
      gload16(gk, lk);                                                        \
      gload16(gk + 1024, lk + 1024);                                          \
      gload16(gk + 2048, lk + 2048);                                          \
      gload16(gk + 3072, lk + 3072);                                          \
      const char* gv = (const char*)(Vb + (((size_t)(kvb) >> 6) << 14) +      \
                                     (((kvb) >> 5) & 1) * 512) +              \
                       w * 8192 + l * 16;                                     \
      char* lv = smem + 16384 + w * 4096;                                     \
      gload16(gv, lv);                                                        \
      gload16(gv + 2048, lv + 1024);                                          \
      gload16(gv + 4096, lv + 2048);                                          \
      gload16(gv + 6144, lv + 3072);                                          \
    }

  if (!direct)
    for (int j = tid; j < chunk; j += 256) mbl[j] = mbb[kv0 + j];

  for (int it = 0; it < niter; ++it) {
    const int kvb = kv0 + (it << 5);
    STAGE(kvb);
    __syncthreads();  // drains vmcnt(0): tile visible to all warps

    // QK^T: S^T[kv][q]
    f32x4 sacc[2];
    sacc[0] = (f32x4){0.f, 0.f, 0.f, 0.f};
    sacc[1] = (f32x4){0.f, 0.f, 0.f, 0.f};
    __builtin_amdgcn_s_setprio(1);
#pragma unroll
    for (int t = 0; t < 2; ++t)
#pragma unroll
      for (int hs = 0; hs < 8; ++hs) {
        bf16x8 kf = *(const bf16x8*)(smem + t * 8192 + hs * 1024 + l * 16);
        sacc[t] = MFMA16(kf, qf[hs], sacc[t]);
      }
    __builtin_amdgcn_s_setprio(0);

    // mask bias + online softmax (8 S-elems/lane)
    f32x4 bias4[2];
#pragma unroll
    for (int t = 0; t < 2; ++t) {
      if (direct)
        bias4[t] = *(const f32x4*)&mbb[kvb + t * 16 + g * 4];
      else
        bias4[t] = *(const f32x4*)&mbl[(it << 5) + t * 16 + g * 4];
    }
    float tmax = -3.4e38f;
#pragma unroll
    for (int t = 0; t < 2; ++t)
#pragma unroll
      for (int r = 0; r < 4; ++r) {
        sacc[t][r] += bias4[t][r];
        tmax = fmaxf(tmax, sacc[t][r]);
      }
    tmax = fmaxf(tmax, __shfl_xor(tmax, 16));
    tmax = fmaxf(tmax, __shfl_xor(tmax, 32));
    if (!__all(tmax <= m + 8.0f)) {  // defer-max rescale
      float mn = fmaxf(m, tmax);
      float f = EXP2(m - mn);
      lsum *= f;
#pragma unroll
      for (int i = 0; i < 16; ++i) {
        oacc[i][0] *= f; oacc[i][1] *= f;
        oacc[i][2] *= f; oacc[i][3] *= f;
      }
      m = mn;
    }
#pragma unroll
    for (int t = 0; t < 2; ++t) {
      float p0 = EXP2(sacc[t][0] - m);
      float p1 = EXP2(sacc[t][1] - m);
      float p2 = EXP2(sacc[t][2] - m);
      float p3 = EXP2(sacc[t][3] - m);
      lsum += (p0 + p1) + (p2 + p3);
      bf16x4 pk;
      pk[0] = (__bf16)p0; pk[1] = (__bf16)p1;
      pk[2] = (__bf16)p2; pk[3] = (__bf16)p3;
      *(bf16x4*)&Pw[lo * 40 + t * 16 + g * 4] = pk;
    }
    // P frag (same-wave LDS write->read)
    bf16x8 pf = *(const bf16x8*)&Pw[lo * 40 + g * 8];

    // PV
    __builtin_amdgcn_s_setprio(1);
#pragma unroll
    for (int ht = 0; ht < 16; ++ht) {
      bf16x8 vf = *(const bf16x8*)(smem + 16384 + ht * 1024 + l * 16);
      oacc[ht] = MFMA16(vf, pf, oacc[ht]);
    }
    __builtin_amdgcn_s_setprio(0);
    __syncthreads();  // all warps done reading before next overwrite
  }

  lsum += __shfl_xor(lsum, 16);
  lsum += __shfl_xor(lsum, 32);
  if (direct) {
    float inv = 1.0f / lsum;
    float* __restrict__ Ob = out + ((size_t)b * 2048 + q0) * 256;
#pragma unroll
    for (int ht = 0; ht < 16; ++ht) {
      f32x4 v = oacc[ht];
      v[0] *= inv; v[1] *= inv; v[2] *= inv; v[3] *= inv;
      *(f32x4*)&Ob[lo * 256 + ht * 16 + g * 4] = v;
    }
  } else {
    const size_t rowbase = (size_t)(s * 8 + b) * 2048 + q0;
    __bf16* __restrict__ Ob = Opart + rowbase * 256;
#pragma unroll
    for (int ht = 0; ht < 16; ++ht) {
      f32x4 v = oacc[ht];
      bf16x4 pk;
      pk[0] = (__bf16)v[0]; pk[1] = (__bf16)v[1];
      pk[2] = (__bf16)v[2]; pk[3] = (__bf16)v[3];
      *(bf16x4*)&Ob[lo * 256 + ht * 16 + g * 4] = pk;
    }
    if (l < 16) {
      mpart[rowbase + lo] = m;
      lpart[rowbase + lo] = lsum;
    }
  }
}

// ---------------------------------------------------------------------------
__global__ __launch_bounds__(256) void combine_kernel(
    const __bf16* __restrict__ Opart, const float* __restrict__ mpart,
    const float* __restrict__ lpart, float* __restrict__ out, int nsplit) {
  int t = blockIdx.x * 256 + threadIdx.x;
  int row = t >> 6;
  int h4 = (t & 63) << 2;
  float M = -3.4e38f;
  for (int s = 0; s < nsplit; ++s) M = fmaxf(M, mpart[s * 16384 + row]);
  f32x4 acc = (f32x4){0.f, 0.f, 0.f, 0.f};
  float denom = 0.f;
  for (int s = 0; s < nsplit; ++s) {
    float wgt = EXP2(mpart[s * 16384 + row] - M);
    denom += wgt * lpart[s * 16384 + row];
    bf16x4 o = *(const bf16x4*)&Opart[((size_t)s * 16384 + row) * 256 + h4];
    acc[0] += wgt * (float)o[0]; acc[1] += wgt * (float)o[1];
    acc[2] += wgt * (float)o[2]; acc[3] += wgt * (float)o[3];
  }
  float inv = 1.0f / denom;
  f32x4 r;
  r[0] = acc[0] * inv; r[1] = acc[1] * inv;
  r[2] = acc[2] * inv; r[3] = acc[3] * inv;
  *(f32x4*)&out[(size_t)row * 256 + h4] = r;
}

// ---------------------------------------------------------------------------
extern "C" void kernel_launch(void* const* d_in, const int* in_sizes, int n_in,
                              void* d_out, int out_size, void* d_ws, size_t ws_size,
                              hipStream_t stream) {
  const float* A = (const float*)d_in[0];
  const float* B = (const float*)d_in[1];
  const int* mask = (const int*)d_in[2];
  const float* Wq = (const float*)d_in[3];
  const float* bq = (const float*)d_in[4];
  const float* Wk = (const float*)d_in[5];
  const float* bk = (const float*)d_in[6];
  const float* Wv = (const float*)d_in[7];
  const float* bv = (const float*)d_in[8];

  char* ws = (char*)d_ws;
  __bf16* QF = (__bf16*)(ws);                         // 8 MB
  __bf16* KF = (__bf16*)(ws + (8ull << 20));          // 8 MB
  __bf16* VF = (__bf16*)(ws + (16ull << 20));         // 8 MB
  float* mb = (float*)(ws + (24ull << 20));           // 64 KB
  float* mpart = (float*)(ws + (24ull << 20) + 0x10000);   // <=256 KB
  float* lpart = (float*)(ws + (24ull << 20) + 0x60000);   // <=256 KB
  __bf16* Wb = (__bf16*)(ws + (24ull << 20) + 0xA0000);    // 384 KB
  __bf16* Opart = (__bf16*)(ws + (25ull << 20));           // S * 8 MB (bf16)

  const size_t base = 25ull << 20;
  const size_t part = 8ull << 20;
  int S;
  if (ws_size >= base + 4 * part) S = 4;
  else if (ws_size >= base + 2 * part) S = 2;
  else if (ws_size >= base + 1 * part) S = 1;
  else S = 0;  // direct mode (no split)

  const int PSMEM = 65536;  // proj: 2 x 32KB W quarter dbuf
  (void)hipFuncSetAttribute((const void*)proj_kernel,
                            hipFuncAttributeMaxDynamicSharedMemorySize, PSMEM);
  const int SMEM = 32768 + 4 * 640 * 2 + 2048;  // 39936 B -> 4 blocks/CU
  (void)hipFuncSetAttribute((const void*)attn_kernel,
                            hipFuncAttributeMaxDynamicSharedMemorySize, SMEM);

  wprep_kernel<<<160, 256, 0, stream>>>(Wq, Wk, Wv, mask, Wb, mb);
  proj_kernel<<<768, 256, PSMEM, stream>>>(A, B, Wb, bq, bk, bv, QF, KF, VF);
  if (S == 0) {
    attn_kernel<<<256, 256, SMEM, stream>>>(QF, KF, VF, mb, nullptr, nullptr,
                                            nullptr, (float*)d_out, 2048, 1);
  } else {
    attn_kernel<<<256 * S, 256, SMEM, stream>>>(QF, KF, VF, mb, Opart, mpart,
                                                lpart, nullptr, 2048 / S, 0);
    combine_kernel<<<4096, 256, 0, stream>>>(Opart, mpart, lpart,
                                             (float*)d_out, S);
  }
}